// Round 4
// baseline (248.919 us; speedup 1.0000x reference)
//
#include <hip/hip_runtime.h>

#define VV 512
#define FF 64
#define OO 64
#define YELEMS 8388608  // shorts per y tensor (256*64*512)

using f32x4 = __attribute__((ext_vector_type(4))) float;
using s16x8 = __attribute__((ext_vector_type(8))) short;
using u16x4 = __attribute__((ext_vector_type(4))) unsigned short;

__device__ __forceinline__ short f2bf(float f) {
    union { float f; unsigned int u; } v; v.f = f;
    unsigned int u = v.u;
    u += 0x7fffu + ((u >> 16) & 1u);
    return (short)(u >> 16);
}
__device__ __forceinline__ float bf2f(unsigned short u) {
    union { unsigned int u; float f; } v; v.u = ((unsigned int)u) << 16; return v.f;
}
__device__ __forceinline__ int swz(int row) { return (row >> 1) & 7; }

// ---------------- Kernel 1: y_k[bt] = x[bt] @ Theta_k, stored TRANSPOSED ----------------
// yT[k][(bt*64 + o)*512 + u]  (bf16)
__global__ __launch_bounds__(256, 4)
void y_kernel(const float* __restrict__ x, const float* __restrict__ Theta,
              unsigned short* __restrict__ yT)
{
    __shared__ __align__(16) unsigned char smem[32768];
    short* xT = (short*)(smem);

    const int tid = threadIdx.x, lane = tid & 63, q = tid >> 6;
    const int g = lane >> 4, nbase = lane & 15;
    const int bt = blockIdx.x >> 3;
    const int u0 = (blockIdx.x & 7) * 64;

    {
        const float* xp = x + ((size_t)(bt * VV + u0 + lane)) * FF + q * 16;
        float4 a0 = ((const float4*)xp)[0];
        float4 a1 = ((const float4*)xp)[1];
        float4 a2 = ((const float4*)xp)[2];
        float4 a3 = ((const float4*)xp)[3];
        float v[16] = {a0.x,a0.y,a0.z,a0.w, a1.x,a1.y,a1.z,a1.w,
                       a2.x,a2.y,a2.z,a2.w, a3.x,a3.y,a3.z,a3.w};
        s16x8 p0, p1;
        #pragma unroll
        for (int e = 0; e < 8; ++e) { p0[e] = f2bf(v[e]); p1[e] = f2bf(v[8 + e]); }
        const int fs = swz(lane);
        *(s16x8*)&xT[lane * 64 + (((q * 2)     ^ fs) * 8)] = p0;
        *(s16x8*)&xT[lane * 64 + (((q * 2 + 1) ^ fs) * 8)] = p1;
    }
    #pragma unroll
    for (int k = 0; k < 3; ++k) {
        short* tk = (short*)(smem + 8192 + k * 8192);
        s16x8 p0, p1;
        #pragma unroll
        for (int e = 0; e < 8; ++e) {
            p0[e] = f2bf(Theta[k * FF * OO + (q * 16 + e) * OO + lane]);
            p1[e] = f2bf(Theta[k * FF * OO + (q * 16 + 8 + e) * OO + lane]);
        }
        const int fs = swz(lane);
        *(s16x8*)&tk[lane * 64 + (((q * 2)     ^ fs) * 8)] = p0;
        *(s16x8*)&tk[lane * 64 + (((q * 2 + 1) ^ fs) * 8)] = p1;
    }
    __syncthreads();

    f32x4 zero = {0.f, 0.f, 0.f, 0.f};
    f32x4 acc[3][4];
    #pragma unroll
    for (int k = 0; k < 3; ++k)
        #pragma unroll
        for (int nt = 0; nt < 4; ++nt) acc[k][nt] = zero;

    const int mrow = q * 16 + nbase;
    const int moff = mrow * 64, ms = swz(mrow);
    #pragma unroll
    for (int kk = 0; kk < 2; ++kk) {
        const int slotA = kk * 4 + g;
        s16x8 a = *(const s16x8*)&xT[moff + ((slotA ^ ms) * 8)];
        #pragma unroll
        for (int nt = 0; nt < 4; ++nt) {
            const int nrow = nt * 16 + nbase;
            const int nad = nrow * 64 + ((slotA ^ swz(nrow)) * 8);
            #pragma unroll
            for (int k = 0; k < 3; ++k) {
                s16x8 b = *(const s16x8*)&((short*)(smem + 8192 + k * 8192))[nad];
                acc[k][nt] = __builtin_amdgcn_mfma_f32_16x16x32_bf16(a, b, acc[k][nt], 0, 0, 0);
            }
        }
    }
    #pragma unroll
    for (int k = 0; k < 3; ++k) {
        #pragma unroll
        for (int nt = 0; nt < 4; ++nt) {
            const int o = nt * 16 + nbase;
            const int u = u0 + q * 16 + g * 4;
            u16x4 pk;
            #pragma unroll
            for (int r = 0; r < 4; ++r) pk[r] = (unsigned short)f2bf(acc[k][nt][r]);
            *(u16x4*)&yT[(size_t)k * YELEMS + ((size_t)(bt * 64 + o)) * VV + u] = pk;
        }
    }
}

// ---------------- Kernel 2: barrier-free fused Chebyshev conv ----------------
// No LDS, no __syncthreads. Each lane computes its A-fragments (coefficients)
// in registers and loads B-fragments (yT) directly from global (L1-shared).
__global__ __launch_bounds__(256, 4)
void cheb_main(const float* __restrict__ S, const float* __restrict__ Att,
               const unsigned short* __restrict__ yT, float* __restrict__ out)
{
    const int tid = threadIdx.x, lane = tid & 63, q = tid >> 6;
    const int g = lane >> 4, nbase = lane & 15;

    // XCD-friendly decode: the 8 v-tiles of one bt share wg%8 -> same XCD
    const int wg = blockIdx.x;
    const int bt = (wg & 7) + ((wg >> 6) << 3);
    const int vt = (wg >> 3) & 7;
    const int v0 = vt * 64;
    const int b  = bt >> 4;

    const float* Sbt = S + (size_t)bt * VV * VV;
    const float* Abt = Att + (size_t)b * VV * VV;
    const unsigned short* y0g = yT + (size_t)bt * 64 * VV;
    const unsigned short* y1g = y0g + (size_t)YELEMS;
    const unsigned short* y2g = y0g + (size_t)2 * YELEMS;

    const int mrow = q * 16 + nbase;   // my A-row (local v)
    const int vg   = v0 + mrow;        // global v
    const float* Srow = Sbt + (size_t)vg * VV;  // S[vg][*]
    const float* Scol = Sbt + vg;               // S[u][vg] at Scol[u*VV]
    const float* Acol = Abt + vg;

    f32x4 zero = {0.f, 0.f, 0.f, 0.f};
    f32x4 acc[4];
    #pragma unroll
    for (int i = 0; i < 4; ++i) acc[i] = zero;
    float da = 0.f, adg = 0.f, sdg = 0.f;

    for (int ut = 0; ut < 8; ++ut) {
        const int u0t = ut * 64;
        #pragma unroll
        for (int kk = 0; kk < 2; ++kk) {
            const int ub = u0t + (kk * 4 + g) * 8;
            // B-fragments first (independent of coefficients)
            s16x8 b1f[4], b2f[4];
            #pragma unroll
            for (int nt = 0; nt < 4; ++nt) {
                const size_t yo = (size_t)(nt * 16 + nbase) * VV + ub;
                b1f[nt] = *(const s16x8*)&y1g[yo];
                b2f[nt] = *(const s16x8*)&y2g[yo];
            }
            // S row chunk (32B contiguous per lane)
            f32x4 r0 = *(const f32x4*)(Srow + ub);
            f32x4 r1 = *(const f32x4*)(Srow + ub + 4);
            // S/A column scalars (16-lane coalesced 64B segments)
            float sc[8], av[8];
            #pragma unroll
            for (int e = 0; e < 8; ++e) {
                sc[e] = Scol[(size_t)(ub + e) * VV];
                av[e] = Acol[(size_t)(ub + e) * VV];
            }
            // coefficients -> A-fragments
            s16x8 a1, a2;
            #pragma unroll
            for (int e = 0; e < 8; ++e) {
                float rv = (e < 4) ? r0[e] : r1[e - 4];
                float sm = fminf(sc[e], rv);
                da += sm;
                float a = av[e];
                float c1 = -a * sm;
                float c2 = (a + a) * (sm * sm);
                if (ub + e == vg) { c1 = 0.f; c2 = 0.f; adg = a; sdg = sm; }
                a1[e] = f2bf(c1);
                a2[e] = f2bf(c2);
            }
            #pragma unroll
            for (int nt = 0; nt < 4; ++nt) {
                acc[nt] = __builtin_amdgcn_mfma_f32_16x16x32_bf16(a1, b1f[nt], acc[nt], 0, 0, 0);
                acc[nt] = __builtin_amdgcn_mfma_f32_16x16x32_bf16(a2, b2f[nt], acc[nt], 0, 0, 0);
            }
        }
    }

    // reduce deg / diag over the 4 g-group lanes (bits 4,5 of lane id)
    da  += __shfl_xor(da, 16);  da  += __shfl_xor(da, 32);
    adg += __shfl_xor(adg, 16); adg += __shfl_xor(adg, 32);
    sdg += __shfl_xor(sdg, 16); sdg += __shfl_xor(sdg, 32);

    float* obt = out + (size_t)bt * VV * OO;
    #pragma unroll
    for (int r = 0; r < 4; ++r) {
        const int vloc = q * 16 + g * 4 + r;   // my C-row (local v)
        const int src  = g * 4 + r;            // lane holding that row's reductions
        const float Ad = __shfl(adg, src);
        const float dv = __shfl(da,  src);
        const float Sd = __shfl(sdg, src);
        const float Ld = dv - Sd - 1.0f;
        const float w1 = Ad * Ld;
        const float w2 = Ad * (2.0f * Ld * Ld - 1.0f);
        const int vgr = v0 + vloc;
        #pragma unroll
        for (int nt = 0; nt < 4; ++nt) {
            const int oo = nt * 16 + nbase;
            const size_t yi = (size_t)oo * VV + vgr;
            float y0v = bf2f(y0g[yi]);
            float y1v = bf2f(y1g[yi]);
            float y2v = bf2f(y2g[yi]);
            float val = acc[nt][r] + Ad * y0v + w1 * y1v + w2 * y2v;
            obt[(size_t)vgr * OO + oo] = fmaxf(val, 0.0f);
        }
    }
}

extern "C" void kernel_launch(void* const* d_in, const int* in_sizes, int n_in,
                              void* d_out, int out_size, void* d_ws, size_t ws_size,
                              hipStream_t stream) {
    (void)in_sizes; (void)n_in; (void)ws_size; (void)out_size;
    const float* x   = (const float*)d_in[0];
    const float* Att = (const float*)d_in[1];
    const float* S   = (const float*)d_in[2];
    const float* Th  = (const float*)d_in[3];
    float* outp = (float*)d_out;
    unsigned short* yT = (unsigned short*)d_ws;  // needs 50,331,648 B
    hipLaunchKernelGGL(y_kernel, dim3(2048), dim3(256), 0, stream, x, Th, yT);
    hipLaunchKernelGGL(cheb_main, dim3(2048), dim3(256), 0, stream, S, Att, yT, outp);
}